// Round 6
// baseline (215.193 us; speedup 1.0000x reference)
//
#include <hip/hip_runtime.h>
#include <math.h>

// Problem constants (B=4, S=2048, D_MODEL=512, H=8, DQ=64)
#define BATCH 4
#define SEQ   2048
#define DM    512
#define NH    8
#define DQ    64
#define BS    (BATCH*SEQ)     // 8192 rows
#define BPAD  72              // bf16 LDS row stride (144 B)
#define APAD  72              // padded A-tile stride in qkv gemm

// q pre-scale: 1/sqrt(64) * log2(e), so softmax uses native 2^x (v_exp_f32)
#define QSCALE 0.18033688011112042f

typedef short  short8  __attribute__((ext_vector_type(8)));
typedef float  floatx4 __attribute__((ext_vector_type(4)));
typedef unsigned short ushort8 __attribute__((ext_vector_type(8)));

// cheap bf16: round-half-up (1 add + shift). Ties-only delta vs RNE.
__device__ __forceinline__ unsigned short f2bf(float f) {
    return (unsigned short)((__float_as_uint(f) + 0x8000u) >> 16);
}
// pack two floats -> two bf16 in one u32 (lo = a, hi = b): 2 adds + 1 v_perm
__device__ __forceinline__ unsigned pack2bf(float a, float b) {
    unsigned ua = __float_as_uint(a) + 0x8000u;
    unsigned ub = __float_as_uint(b) + 0x8000u;
    return __builtin_amdgcn_perm(ub, ua, 0x07060302u);  // {ub[3],ub[2],ua[3],ua[2]}
}

__device__ __forceinline__ void async_copy16(const void* g, void* l) {
    __builtin_amdgcn_global_load_lds(
        (const __attribute__((address_space(1))) unsigned int*)g,
        (__attribute__((address_space(3))) unsigned int*)l, 16, 0, 0);
}

// ---------------------------------------------------------------------------
// convert_w: pack weights to bf16 B^T layout [n][k].
//   which 0..2: wt[which][h*64+d][dd] = W[h][dd][d]  (qkv projections)
//   which 3:    wo[o][c] = Wout[o][c]                 (already B^T)
// grid (256, 4).
// ---------------------------------------------------------------------------
__global__ __launch_bounds__(256) void convert_w_kernel(
    const float* __restrict__ Wq, const float* __restrict__ Wk,
    const float* __restrict__ Wv, const float* __restrict__ Wo,
    unsigned short* __restrict__ wt, unsigned short* __restrict__ wo)
{
    const int which = blockIdx.y;
    const int idx = blockIdx.x * 256 + threadIdx.x;   // 65536 per matrix
    if (which == 3) {
        float4 v = *(const float4*)(Wo + (size_t)idx * 4);
        uint2 o;
        o.x = pack2bf(v.x, v.y);
        o.y = pack2bf(v.z, v.w);
        *(uint2*)(wo + (size_t)idx * 4) = o;
    } else {
        const float* W = (which == 0) ? Wq : (which == 1) ? Wk : Wv;
        const int n   = idx >> 7;          // 0..511  (h*64+d)
        const int dd0 = (idx & 127) * 4;
        const int h = n >> 6, d = n & 63;
        uint2 o;
        o.x = pack2bf(W[((size_t)h * DM + dd0 + 0) * DQ + d],
                      W[((size_t)h * DM + dd0 + 1) * DQ + d]);
        o.y = pack2bf(W[((size_t)h * DM + dd0 + 2) * DQ + d],
                      W[((size_t)h * DM + dd0 + 3) * DQ + d]);
        *(uint2*)(wt + (size_t)which * (DM * DM) + (size_t)n * DM + dd0) = o;
    }
}

// ---------------------------------------------------------------------------
// qkv GEMM with fused fp32->bf16 conversion of x during A-staging.
// A = x fp32 [8192x512] (loaded directly), Bt = packed bf16 weights [512x512].
// 128x128 tile, BK=64. A staged manually into padded LDS; B via
// global_load_lds. Outputs: which 0 -> q*QSCALE bf16 [b,h,s,d];
// 1 -> k bf16 [b,h,s,d]; 2 -> v bf16 [b,h,d,s].
// grid (64, 4, 3), block 256.
// ---------------------------------------------------------------------------
__global__ __launch_bounds__(256) void qkv_gemm_kernel(
    const float* __restrict__ Xq, const float* __restrict__ Xk,
    const float* __restrict__ Xv, const unsigned short* __restrict__ wt,
    unsigned short* __restrict__ Oq, unsigned short* __restrict__ Ok,
    unsigned short* __restrict__ Ovt)
{
    __shared__ unsigned short As[128][APAD];   // padded: frag reads conflict-free
    __shared__ unsigned short Bs[128][64];     // global_load_lds target

    const int which = blockIdx.z;
    const float* X = (which == 0) ? Xq : (which == 1) ? Xk : Xv;
    const unsigned short* Bt = wt + (size_t)which * (DM * DM);

    const int m0 = blockIdx.x * 128;
    const int n0 = blockIdx.y * 128;
    const int t = threadIdx.x, w = t >> 6, lane = t & 63;
    const int quad = lane >> 4, qr = lane & 15;
    const int lr = lane >> 3;          // B-staging row within 8-row group
    const int lc = (lane & 7) * 8;     // B-staging col (bf16 elems)
    const int arow = t >> 4;           // A-staging: 16 rows per pass
    const int acol = (t & 15) * 4;     // A-staging: float4 column
    const int mw = 64 * (w >> 1), nw = 64 * (w & 1);

    floatx4 acc[4][4] = {};

    for (int k0 = 0; k0 < DM; k0 += 64) {
        // B: async DMA (4 chunks/thread)
        #pragma unroll
        for (int i = 0; i < 4; ++i) {
            const int row = i * 32 + w * 8;
            async_copy16(Bt + (size_t)(n0 + row + lr) * DM + k0 + lc, &Bs[row][0]);
        }
        // A: fp32 load + pack + manual staging (8 passes of 16 rows)
        #pragma unroll
        for (int i = 0; i < 8; ++i) {
            const int row = i * 16 + arow;
            float4 x4 = *(const float4*)(X + (size_t)(m0 + row) * DM + k0 + acol);
            uint2 o;
            o.x = pack2bf(x4.x, x4.y);
            o.y = pack2bf(x4.z, x4.w);
            *(uint2*)&As[row][acol] = o;
        }
        __syncthreads();
        #pragma unroll
        for (int kh = 0; kh < 2; ++kh) {
            short8 af[4], bf[4];
            #pragma unroll
            for (int si = 0; si < 4; ++si)
                af[si] = *(const short8*)&As[mw + 16 * si + qr][kh * 32 + quad * 8];
            #pragma unroll
            for (int sj = 0; sj < 4; ++sj)
                bf[sj] = *(const short8*)&Bs[nw + 16 * sj + qr][kh * 32 + quad * 8];
            #pragma unroll
            for (int si = 0; si < 4; ++si)
                #pragma unroll
                for (int sj = 0; sj < 4; ++sj)
                    acc[si][sj] = __builtin_amdgcn_mfma_f32_16x16x32_bf16(
                        af[si], bf[sj], acc[si][sj], 0, 0, 0);
        }
        __syncthreads();
    }

    const float osc = (which == 0) ? QSCALE : 1.0f;
    if (which < 2) {
        unsigned short* O = (which == 0) ? Oq : Ok;
        #pragma unroll
        for (int si = 0; si < 4; ++si) {
            #pragma unroll
            for (int sj = 0; sj < 4; ++sj) {
                const int col = n0 + nw + 16 * sj + qr;
                const int h = col >> 6, d = col & 63;
                #pragma unroll
                for (int r = 0; r < 4; ++r) {
                    const int row = m0 + mw + 16 * si + quad * 4 + r;
                    const int b = row >> 11, s = row & (SEQ - 1);
                    O[((size_t)(b * NH + h) * SEQ + s) * DQ + d] = f2bf(acc[si][sj][r] * osc);
                }
            }
        }
    } else {
        #pragma unroll
        for (int si = 0; si < 4; ++si) {
            #pragma unroll
            for (int sj = 0; sj < 4; ++sj) {
                const int col = n0 + nw + 16 * sj + qr;
                const int h = col >> 6, d = col & 63;
                #pragma unroll
                for (int r = 0; r < 4; ++r) {
                    const int row = m0 + mw + 16 * si + quad * 4 + r;
                    const int b = row >> 11, s = row & (SEQ - 1);
                    Ovt[((size_t)(b * NH + h) * DQ + d) * SEQ + s] = f2bf(acc[si][sj][r]);
                }
            }
        }
    }
}

// ---------------------------------------------------------------------------
// out GEMM: bf16 MFMA. A = heads bf16 [8192x512] (flat view == reference
// reshape), Bt = Wout bf16 [o][c]. Output fp32 d_out [8192x512].
// grid (64, 4), block 256.
// ---------------------------------------------------------------------------
__global__ __launch_bounds__(256) void out_gemm_kernel(
    const unsigned short* __restrict__ A, const unsigned short* __restrict__ Bt,
    float* __restrict__ C)
{
    __shared__ unsigned short As[128][64];
    __shared__ unsigned short Bs[128][64];

    const int m0 = blockIdx.x * 128;
    const int n0 = blockIdx.y * 128;
    const int t = threadIdx.x, w = t >> 6, lane = t & 63;
    const int quad = lane >> 4, qr = lane & 15;
    const int lr = lane >> 3;
    const int lc = (lane & 7) * 8;
    const int mw = 64 * (w >> 1), nw = 64 * (w & 1);

    floatx4 acc[4][4] = {};

    for (int k0 = 0; k0 < DM; k0 += 64) {
        #pragma unroll
        for (int i = 0; i < 4; ++i) {
            const int row = i * 32 + w * 8;
            async_copy16(A  + (size_t)(m0 + row + lr) * DM + k0 + lc, &As[row][0]);
            async_copy16(Bt + (size_t)(n0 + row + lr) * DM + k0 + lc, &Bs[row][0]);
        }
        __syncthreads();
        #pragma unroll
        for (int kh = 0; kh < 2; ++kh) {
            short8 af[4], bf[4];
            #pragma unroll
            for (int si = 0; si < 4; ++si)
                af[si] = *(const short8*)&As[mw + 16 * si + qr][kh * 32 + quad * 8];
            #pragma unroll
            for (int sj = 0; sj < 4; ++sj)
                bf[sj] = *(const short8*)&Bs[nw + 16 * sj + qr][kh * 32 + quad * 8];
            #pragma unroll
            for (int si = 0; si < 4; ++si)
                #pragma unroll
                for (int sj = 0; sj < 4; ++sj)
                    acc[si][sj] = __builtin_amdgcn_mfma_f32_16x16x32_bf16(
                        af[si], bf[sj], acc[si][sj], 0, 0, 0);
        }
        __syncthreads();
    }

    #pragma unroll
    for (int si = 0; si < 4; ++si) {
        #pragma unroll
        for (int sj = 0; sj < 4; ++sj) {
            const int col = n0 + nw + 16 * sj + qr;
            #pragma unroll
            for (int r = 0; r < 4; ++r) {
                const int row = m0 + mw + 16 * si + quad * 4 + r;
                C[(size_t)row * DM + col] = acc[si][sj][r];
            }
        }
    }
}

// ---------------------------------------------------------------------------
// flash attention v4: 64-row q-tile (best-measured occupancy: 36 KB LDS ->
// 4 blocks/CU), fixed-reference base-2 softmax (q pre-scaled by 0.125*log2e),
// S^T orientation (P stores = ds_write_b64), K/V register prefetch, and
// v_perm-packed bf16 P (3 VALU per 2 elems — kernel is VALU-issue bound).
// grid = (32 q-tiles, 8 heads, 4 batch), block = 256 (4 waves).
// Wave w owns q-rows 16w..16w+15.
// ---------------------------------------------------------------------------
__global__ __launch_bounds__(256) void attn_kernel(
    const unsigned short* __restrict__ Qp, const unsigned short* __restrict__ Kp,
    const unsigned short* __restrict__ Vtp, unsigned short* __restrict__ Hd)
{
    __shared__ unsigned short Qs[64][BPAD];   // [s][d]
    __shared__ unsigned short Ks[64][BPAD];   // [kv][d]
    __shared__ unsigned short Vts[64][BPAD];  // [d][kv]
    __shared__ unsigned short Ps[64][BPAD];   // [q-row][kv] bf16

    const int s0 = blockIdx.x * 64;
    const int h  = blockIdx.y;
    const int b  = blockIdx.z;
    const size_t bh    = (size_t)(b * NH + h);
    const size_t base  = bh * SEQ * DQ;       // [b,h,s,d]
    const size_t vbase = bh * DQ * SEQ;       // [b,h,d,s]

    const int t    = threadIdx.x;
    const int w    = t >> 6;
    const int lane = t & 63;
    const int quad = lane >> 4;
    const int qr   = lane & 15;

    // ---- stage Q tile ----
    {
        const unsigned short* g = Qp + base + (size_t)s0 * DQ;
        #pragma unroll
        for (int i = 0; i < 2; ++i) {
            const int c = t + 256 * i;
            const int row = c >> 3, col8 = (c & 7) * 8;
            *(ushort8*)&Qs[row][col8] = *(const ushort8*)(g + row * DQ + col8);
        }
    }
    __syncthreads();
    const short8 aq0 = *(const short8*)&Qs[16 * w + qr][quad * 8];
    const short8 aq1 = *(const short8*)&Qs[16 * w + qr][quad * 8 + 32];

    floatx4 acc_o[4] = {};
    float l_lane = 0.f;

    // ---- prefetch first K/V tile into registers ----
    ushort8 kreg[2], vreg[2];
    {
        const unsigned short* gk = Kp + base;
        const unsigned short* gv = Vtp + vbase;
        #pragma unroll
        for (int i = 0; i < 2; ++i) {
            const int c = t + 256 * i;
            const int row = c >> 3, col8 = (c & 7) * 8;
            kreg[i] = *(const ushort8*)(gk + row * DQ + col8);
            vreg[i] = *(const ushort8*)(gv + (size_t)row * SEQ + col8);
        }
    }

    for (int kt = 0; kt < SEQ; kt += 64) {
        __syncthreads();   // prev iteration's reads of Ks/Vts complete
        #pragma unroll
        for (int i = 0; i < 2; ++i) {
            const int c = t + 256 * i;
            const int row = c >> 3, col8 = (c & 7) * 8;
            *(ushort8*)&Ks[row][col8]  = kreg[i];
            *(ushort8*)&Vts[row][col8] = vreg[i];
        }
        __syncthreads();

        // issue next tile's global loads (overlap with MFMA below)
        if (kt + 64 < SEQ) {
            const unsigned short* gk = Kp + base + (size_t)(kt + 64) * DQ;
            const unsigned short* gv = Vtp + vbase + (kt + 64);
            #pragma unroll
            for (int i = 0; i < 2; ++i) {
                const int c = t + 256 * i;
                const int row = c >> 3, col8 = (c & 7) * 8;
                kreg[i] = *(const ushort8*)(gk + row * DQ + col8);
                vreg[i] = *(const ushort8*)(gv + (size_t)row * SEQ + col8);
            }
        }

        // ---- S^T = K @ Q^T per kv-subtile si; exp2; pack P.
        // C-layout: lane holds kv = 16si+quad*4+{0..3}, qrow = 16w+qr.
        #pragma unroll
        for (int si = 0; si < 4; ++si) {
            const short8 ak0 = *(const short8*)&Ks[16 * si + qr][quad * 8];
            const short8 ak1 = *(const short8*)&Ks[16 * si + qr][quad * 8 + 32];
            floatx4 z = {0.f, 0.f, 0.f, 0.f};
            z = __builtin_amdgcn_mfma_f32_16x16x32_bf16(ak0, aq0, z, 0, 0, 0);
            z = __builtin_amdgcn_mfma_f32_16x16x32_bf16(ak1, aq1, z, 0, 0, 0);
            const float p0 = exp2f(z[0]), p1 = exp2f(z[1]);
            const float p2 = exp2f(z[2]), p3 = exp2f(z[3]);
            l_lane += (p0 + p1) + (p2 + p3);
            uint2 pk;
            pk.x = pack2bf(p0, p1);
            pk.y = pack2bf(p2, p3);
            *(uint2*)&Ps[16 * w + qr][16 * si + quad * 4] = pk;   // ds_write_b64
        }

        // ---- PV: acc_o[c] += P @ V (wave-private Ps, no barrier) ----
        const short8 ap0 = *(const short8*)&Ps[16 * w + qr][quad * 8];
        const short8 ap1 = *(const short8*)&Ps[16 * w + qr][quad * 8 + 32];
        #pragma unroll
        for (int c = 0; c < 4; ++c) {
            const short8 bv0 = *(const short8*)&Vts[16 * c + qr][quad * 8];
            const short8 bv1 = *(const short8*)&Vts[16 * c + qr][quad * 8 + 32];
            acc_o[c] = __builtin_amdgcn_mfma_f32_16x16x32_bf16(ap0, bv0, acc_o[c], 0, 0, 0);
            acc_o[c] = __builtin_amdgcn_mfma_f32_16x16x32_bf16(ap1, bv1, acc_o[c], 0, 0, 0);
        }
    }

    // ---- final l reduction (across the 4 quads holding each qrow) ----
    l_lane += __shfl_xor(l_lane, 16);
    l_lane += __shfl_xor(l_lane, 32);
    float inv_l[4];
    #pragma unroll
    for (int r = 0; r < 4; ++r)
        inv_l[r] = 1.0f / __shfl(l_lane, quad * 4 + r);

    #pragma unroll
    for (int c = 0; c < 4; ++c)
        #pragma unroll
        for (int r = 0; r < 4; ++r)
            Hd[base + (size_t)(s0 + 16 * w + quad * 4 + r) * DQ + 16 * c + qr] =
                f2bf(acc_o[c][r] * inv_l[r]);
}

// ---------------------------------------------------------------------------
// kernel_launch
// Workspace (ushort units):
//   wt:    0        (3 x 262144)    qkv weights bf16, B^T [h*64+d][dd]
//   wo:    786432   (262144)        Wout bf16 [o][c]
//   q_ws:  1048576  (4194304)       q*QSCALE bf16 [b,h,s,d]
//   k_ws:  5242880  (4194304)       k bf16 [b,h,s,d]
//   vt_ws: 9437184  (4194304)       v bf16 [b,h,d,s]
//   h_ws:  13631488 (4194304)       heads bf16 (flat GEMM-A view)
// total ~34 MB
// ---------------------------------------------------------------------------
extern "C" void kernel_launch(void* const* d_in, const int* in_sizes, int n_in,
                              void* d_out, int out_size, void* d_ws, size_t ws_size,
                              hipStream_t stream) {
    const float* xq = (const float*)d_in[0];
    const float* xk = (const float*)d_in[1];
    const float* xv = (const float*)d_in[2];
    const float* Qw = (const float*)d_in[3];
    const float* Kw = (const float*)d_in[4];
    const float* Vw = (const float*)d_in[5];
    const float* Wo = (const float*)d_in[6];
    float* out = (float*)d_out;

    unsigned short* ws = (unsigned short*)d_ws;
    unsigned short* wt    = ws;
    unsigned short* wo    = ws + (size_t)786432;
    unsigned short* q_ws  = ws + (size_t)1048576;
    unsigned short* k_ws  = ws + (size_t)5242880;
    unsigned short* vt_ws = ws + (size_t)9437184;
    unsigned short* h_ws  = ws + (size_t)13631488;

    convert_w_kernel<<<dim3(256, 4), 256, 0, stream>>>(Qw, Kw, Vw, Wo, wt, wo);
    qkv_gemm_kernel<<<dim3(64, 4, 3), 256, 0, stream>>>(xq, xk, xv, wt, q_ws, k_ws, vt_ws);
    attn_kernel<<<dim3(SEQ / 64, NH, BATCH), 256, 0, stream>>>(q_ws, k_ws, vt_ws, h_ws);
    out_gemm_kernel<<<dim3(64, 4), 256, 0, stream>>>(h_ws, wo, out);
}

// Round 7
// 196.999 us; speedup vs baseline: 1.0924x; 1.0924x over previous
//
#include <hip/hip_runtime.h>
#include <math.h>

// Problem constants (B=4, S=2048, D_MODEL=512, H=8, DQ=64)
#define BATCH 4
#define SEQ   2048
#define DM    512
#define NH    8
#define DQ    64
#define BS    (BATCH*SEQ)     // 8192 rows
#define BPAD  72              // bf16 LDS row stride (144 B)
#define APAD  72              // padded tile stride in gemms

// q pre-scale: 1/sqrt(64) * log2(e), so softmax uses native 2^x (v_exp_f32)
#define QSCALE 0.18033688011112042f

typedef short  short8  __attribute__((ext_vector_type(8)));
typedef float  floatx4 __attribute__((ext_vector_type(4)));
typedef unsigned short ushort8 __attribute__((ext_vector_type(8)));

// cheap bf16: round-half-up (1 add + shift). Ties-only delta vs RNE.
__device__ __forceinline__ unsigned short f2bf(float f) {
    return (unsigned short)((__float_as_uint(f) + 0x8000u) >> 16);
}
// pack two floats -> two bf16 in one u32 (lo = a, hi = b): 2 adds + 1 v_perm
__device__ __forceinline__ unsigned pack2bf(float a, float b) {
    unsigned ua = __float_as_uint(a) + 0x8000u;
    unsigned ub = __float_as_uint(b) + 0x8000u;
    return __builtin_amdgcn_perm(ub, ua, 0x07060302u);  // {ub[3],ub[2],ua[3],ua[2]}
}

// ---------------------------------------------------------------------------
// convert_w: pack weights to bf16 B^T layout [n][k].
//   which 0..2: wt[which][h*64+d][dd] = W[h][dd][d]  (qkv projections)
//   which 3:    wo[o][c] = Wout[o][c]                 (already B^T)
// grid (256, 4).
// ---------------------------------------------------------------------------
__global__ __launch_bounds__(256) void convert_w_kernel(
    const float* __restrict__ Wq, const float* __restrict__ Wk,
    const float* __restrict__ Wv, const float* __restrict__ Wo,
    unsigned short* __restrict__ wt, unsigned short* __restrict__ wo)
{
    const int which = blockIdx.y;
    const int idx = blockIdx.x * 256 + threadIdx.x;   // 65536 per matrix
    if (which == 3) {
        float4 v = *(const float4*)(Wo + (size_t)idx * 4);
        uint2 o;
        o.x = pack2bf(v.x, v.y);
        o.y = pack2bf(v.z, v.w);
        *(uint2*)(wo + (size_t)idx * 4) = o;
    } else {
        const float* W = (which == 0) ? Wq : (which == 1) ? Wk : Wv;
        const int n   = idx >> 7;          // 0..511  (h*64+d)
        const int dd0 = (idx & 127) * 4;
        const int h = n >> 6, d = n & 63;
        uint2 o;
        o.x = pack2bf(W[((size_t)h * DM + dd0 + 0) * DQ + d],
                      W[((size_t)h * DM + dd0 + 1) * DQ + d]);
        o.y = pack2bf(W[((size_t)h * DM + dd0 + 2) * DQ + d],
                      W[((size_t)h * DM + dd0 + 3) * DQ + d]);
        *(uint2*)(wt + (size_t)which * (DM * DM) + (size_t)n * DM + dd0) = o;
    }
}

// ---------------------------------------------------------------------------
// qkv GEMM: 128x128 tile, BK=64, K=512 (8 k-steps). Both A (fp32 x, packed
// to bf16 at store) and B (bf16 weights) are REGISTER-PREFETCHED across the
// stage barrier: loads for step k+1 issue right after the barrier and drain
// during the MFMA phase — with only 8 k-steps the m97-style vmcnt(0) drain
// would otherwise be exposed every step.
// Outputs: which 0 -> q*QSCALE bf16 [b,h,s,d]; 1 -> k bf16 [b,h,s,d];
//          2 -> v bf16 [b,h,d,s].
// grid (64, 4, 3) = 768 blocks (3/CU), block 256.
// ---------------------------------------------------------------------------
__global__ __launch_bounds__(256) void qkv_gemm_kernel(
    const float* __restrict__ Xq, const float* __restrict__ Xk,
    const float* __restrict__ Xv, const unsigned short* __restrict__ wt,
    unsigned short* __restrict__ Oq, unsigned short* __restrict__ Ok,
    unsigned short* __restrict__ Ovt)
{
    __shared__ unsigned short As[128][APAD];
    __shared__ unsigned short Bs[128][APAD];

    const int which = blockIdx.z;
    const float* X = (which == 0) ? Xq : (which == 1) ? Xk : Xv;
    const unsigned short* Bt = wt + (size_t)which * (DM * DM);

    const int m0 = blockIdx.x * 128;
    const int n0 = blockIdx.y * 128;
    const int t = threadIdx.x, w = t >> 6, lane = t & 63;
    const int quad = lane >> 4, qr = lane & 15;
    const int arow = t >> 4;           // A staging: 16 rows/pass
    const int acol = (t & 15) * 4;     // float4 col
    const int brow = t >> 3;           // B staging: 32 rows/pass
    const int bcol = (t & 7) * 8;      // ushort8 col
    const int mw = 64 * (w >> 1), nw = 64 * (w & 1);

    floatx4 acc[4][4] = {};
    float4  areg[8];
    ushort8 breg[4];

    // prefetch k0 = 0
    #pragma unroll
    for (int i = 0; i < 8; ++i)
        areg[i] = *(const float4*)(X + (size_t)(m0 + i * 16 + arow) * DM + acol);
    #pragma unroll
    for (int i = 0; i < 4; ++i)
        breg[i] = *(const ushort8*)(Bt + (size_t)(n0 + i * 32 + brow) * DM + bcol);

    for (int k0 = 0; k0 < DM; k0 += 64) {
        __syncthreads();   // prev step's fragment reads complete
        #pragma unroll
        for (int i = 0; i < 8; ++i) {
            uint2 o;
            o.x = pack2bf(areg[i].x, areg[i].y);
            o.y = pack2bf(areg[i].z, areg[i].w);
            *(uint2*)&As[i * 16 + arow][acol] = o;
        }
        #pragma unroll
        for (int i = 0; i < 4; ++i)
            *(ushort8*)&Bs[i * 32 + brow][bcol] = breg[i];
        __syncthreads();

        // issue next step's global loads (overlap with MFMA below)
        if (k0 + 64 < DM) {
            #pragma unroll
            for (int i = 0; i < 8; ++i)
                areg[i] = *(const float4*)(X + (size_t)(m0 + i * 16 + arow) * DM + k0 + 64 + acol);
            #pragma unroll
            for (int i = 0; i < 4; ++i)
                breg[i] = *(const ushort8*)(Bt + (size_t)(n0 + i * 32 + brow) * DM + k0 + 64 + bcol);
        }

        #pragma unroll
        for (int kh = 0; kh < 2; ++kh) {
            short8 af[4], bf[4];
            #pragma unroll
            for (int si = 0; si < 4; ++si)
                af[si] = *(const short8*)&As[mw + 16 * si + qr][kh * 32 + quad * 8];
            #pragma unroll
            for (int sj = 0; sj < 4; ++sj)
                bf[sj] = *(const short8*)&Bs[nw + 16 * sj + qr][kh * 32 + quad * 8];
            #pragma unroll
            for (int si = 0; si < 4; ++si)
                #pragma unroll
                for (int sj = 0; sj < 4; ++sj)
                    acc[si][sj] = __builtin_amdgcn_mfma_f32_16x16x32_bf16(
                        af[si], bf[sj], acc[si][sj], 0, 0, 0);
        }
    }

    const float osc = (which == 0) ? QSCALE : 1.0f;
    if (which < 2) {
        unsigned short* O = (which == 0) ? Oq : Ok;
        #pragma unroll
        for (int si = 0; si < 4; ++si) {
            #pragma unroll
            for (int sj = 0; sj < 4; ++sj) {
                const int col = n0 + nw + 16 * sj + qr;
                const int h = col >> 6, d = col & 63;
                #pragma unroll
                for (int r = 0; r < 4; ++r) {
                    const int row = m0 + mw + 16 * si + quad * 4 + r;
                    const int b = row >> 11, s = row & (SEQ - 1);
                    O[((size_t)(b * NH + h) * SEQ + s) * DQ + d] = f2bf(acc[si][sj][r] * osc);
                }
            }
        }
    } else {
        #pragma unroll
        for (int si = 0; si < 4; ++si) {
            #pragma unroll
            for (int sj = 0; sj < 4; ++sj) {
                const int col = n0 + nw + 16 * sj + qr;
                const int h = col >> 6, d = col & 63;
                #pragma unroll
                for (int r = 0; r < 4; ++r) {
                    const int row = m0 + mw + 16 * si + quad * 4 + r;
                    const int b = row >> 11, s = row & (SEQ - 1);
                    Ovt[((size_t)(b * NH + h) * DQ + d) * SEQ + s] = f2bf(acc[si][sj][r]);
                }
            }
        }
    }
}

// ---------------------------------------------------------------------------
// out GEMM: 64x128 tile (512 blocks = 2/CU — the old 128x128 ran at exactly
// 1 block/CU with zero drain overlap), BK=64, register-prefetched staging.
// A = heads bf16 [8192x512] (flat view == reference reshape), Bt = Wout bf16
// [o][c]. Output fp32 d_out. grid (128, 4), block 256; wave tile 32x64.
// ---------------------------------------------------------------------------
__global__ __launch_bounds__(256) void out_gemm_kernel(
    const unsigned short* __restrict__ A, const unsigned short* __restrict__ Bt,
    float* __restrict__ C)
{
    __shared__ unsigned short As[64][APAD];
    __shared__ unsigned short Bs[128][APAD];

    const int m0 = blockIdx.x * 64;
    const int n0 = blockIdx.y * 128;
    const int t = threadIdx.x, w = t >> 6, lane = t & 63;
    const int quad = lane >> 4, qr = lane & 15;
    const int brow = t >> 3;           // 32 rows/pass
    const int bcol = (t & 7) * 8;
    const int mw = 32 * (w >> 1), nw = 64 * (w & 1);

    floatx4 acc[2][4] = {};
    ushort8 areg[2], breg[4];

    #pragma unroll
    for (int i = 0; i < 2; ++i)
        areg[i] = *(const ushort8*)(A + (size_t)(m0 + i * 32 + brow) * DM + bcol);
    #pragma unroll
    for (int i = 0; i < 4; ++i)
        breg[i] = *(const ushort8*)(Bt + (size_t)(n0 + i * 32 + brow) * DM + bcol);

    for (int k0 = 0; k0 < DM; k0 += 64) {
        __syncthreads();
        #pragma unroll
        for (int i = 0; i < 2; ++i)
            *(ushort8*)&As[i * 32 + brow][bcol] = areg[i];
        #pragma unroll
        for (int i = 0; i < 4; ++i)
            *(ushort8*)&Bs[i * 32 + brow][bcol] = breg[i];
        __syncthreads();

        if (k0 + 64 < DM) {
            #pragma unroll
            for (int i = 0; i < 2; ++i)
                areg[i] = *(const ushort8*)(A + (size_t)(m0 + i * 32 + brow) * DM + k0 + 64 + bcol);
            #pragma unroll
            for (int i = 0; i < 4; ++i)
                breg[i] = *(const ushort8*)(Bt + (size_t)(n0 + i * 32 + brow) * DM + k0 + 64 + bcol);
        }

        #pragma unroll
        for (int kh = 0; kh < 2; ++kh) {
            short8 af[2], bf[4];
            #pragma unroll
            for (int si = 0; si < 2; ++si)
                af[si] = *(const short8*)&As[mw + 16 * si + qr][kh * 32 + quad * 8];
            #pragma unroll
            for (int sj = 0; sj < 4; ++sj)
                bf[sj] = *(const short8*)&Bs[nw + 16 * sj + qr][kh * 32 + quad * 8];
            #pragma unroll
            for (int si = 0; si < 2; ++si)
                #pragma unroll
                for (int sj = 0; sj < 4; ++sj)
                    acc[si][sj] = __builtin_amdgcn_mfma_f32_16x16x32_bf16(
                        af[si], bf[sj], acc[si][sj], 0, 0, 0);
        }
    }

    #pragma unroll
    for (int si = 0; si < 2; ++si) {
        #pragma unroll
        for (int sj = 0; sj < 4; ++sj) {
            const int col = n0 + nw + 16 * sj + qr;
            #pragma unroll
            for (int r = 0; r < 4; ++r) {
                const int row = m0 + mw + 16 * si + quad * 4 + r;
                C[(size_t)row * DM + col] = acc[si][sj][r];
            }
        }
    }
}

// ---------------------------------------------------------------------------
// flash attention v5: 64-row q-tile (36 KB LDS -> 4 blocks/CU), fixed-
// reference base-2 softmax via RAW v_exp_f32 (__builtin_amdgcn_exp2f — libm
// exp2f lowers to an OCML call with denorm fixup that cost ~8 µs in R5/R6),
// S^T orientation (P stores = ds_write_b64), K/V register prefetch,
// v_perm-packed bf16 P. grid = (32, 8, 4), block 256 (4 waves).
// Wave w owns q-rows 16w..16w+15. q pre-scaled by 0.125*log2(e).
// ---------------------------------------------------------------------------
__global__ __launch_bounds__(256) void attn_kernel(
    const unsigned short* __restrict__ Qp, const unsigned short* __restrict__ Kp,
    const unsigned short* __restrict__ Vtp, unsigned short* __restrict__ Hd)
{
    __shared__ unsigned short Qs[64][BPAD];   // [s][d]
    __shared__ unsigned short Ks[64][BPAD];   // [kv][d]
    __shared__ unsigned short Vts[64][BPAD];  // [d][kv]
    __shared__ unsigned short Ps[64][BPAD];   // [q-row][kv] bf16

    const int s0 = blockIdx.x * 64;
    const int h  = blockIdx.y;
    const int b  = blockIdx.z;
    const size_t bh    = (size_t)(b * NH + h);
    const size_t base  = bh * SEQ * DQ;       // [b,h,s,d]
    const size_t vbase = bh * DQ * SEQ;       // [b,h,d,s]

    const int t    = threadIdx.x;
    const int w    = t >> 6;
    const int lane = t & 63;
    const int quad = lane >> 4;
    const int qr   = lane & 15;

    // ---- stage Q tile ----
    {
        const unsigned short* g = Qp + base + (size_t)s0 * DQ;
        #pragma unroll
        for (int i = 0; i < 2; ++i) {
            const int c = t + 256 * i;
            const int row = c >> 3, col8 = (c & 7) * 8;
            *(ushort8*)&Qs[row][col8] = *(const ushort8*)(g + row * DQ + col8);
        }
    }
    __syncthreads();
    const short8 aq0 = *(const short8*)&Qs[16 * w + qr][quad * 8];
    const short8 aq1 = *(const short8*)&Qs[16 * w + qr][quad * 8 + 32];

    floatx4 acc_o[4] = {};
    float l_lane = 0.f;

    // ---- prefetch first K/V tile into registers ----
    ushort8 kreg[2], vreg[2];
    {
        const unsigned short* gk = Kp + base;
        const unsigned short* gv = Vtp + vbase;
        #pragma unroll
        for (int i = 0; i < 2; ++i) {
            const int c = t + 256 * i;
            const int row = c >> 3, col8 = (c & 7) * 8;
            kreg[i] = *(const ushort8*)(gk + row * DQ + col8);
            vreg[i] = *(const ushort8*)(gv + (size_t)row * SEQ + col8);
        }
    }

    for (int kt = 0; kt < SEQ; kt += 64) {
        __syncthreads();   // prev iteration's reads of Ks/Vts complete
        #pragma unroll
        for (int i = 0; i < 2; ++i) {
            const int c = t + 256 * i;
            const int row = c >> 3, col8 = (c & 7) * 8;
            *(ushort8*)&Ks[row][col8]  = kreg[i];
            *(ushort8*)&Vts[row][col8] = vreg[i];
        }
        __syncthreads();

        // issue next tile's global loads (overlap with MFMA below)
        if (kt + 64 < SEQ) {
            const unsigned short* gk = Kp + base + (size_t)(kt + 64) * DQ;
            const unsigned short* gv = Vtp + vbase + (kt + 64);
            #pragma unroll
            for (int i = 0; i < 2; ++i) {
                const int c = t + 256 * i;
                const int row = c >> 3, col8 = (c & 7) * 8;
                kreg[i] = *(const ushort8*)(gk + row * DQ + col8);
                vreg[i] = *(const ushort8*)(gv + (size_t)row * SEQ + col8);
            }
        }

        // ---- S^T = K @ Q^T per kv-subtile si; raw v_exp_f32; pack P.
        // C-layout: lane holds kv = 16si+quad*4+{0..3}, qrow = 16w+qr.
        #pragma unroll
        for (int si = 0; si < 4; ++si) {
            const short8 ak0 = *(const short8*)&Ks[16 * si + qr][quad * 8];
            const short8 ak1 = *(const short8*)&Ks[16 * si + qr][quad * 8 + 32];
            floatx4 z = {0.f, 0.f, 0.f, 0.f};
            z = __builtin_amdgcn_mfma_f32_16x16x32_bf16(ak0, aq0, z, 0, 0, 0);
            z = __builtin_amdgcn_mfma_f32_16x16x32_bf16(ak1, aq1, z, 0, 0, 0);
            const float p0 = __builtin_amdgcn_exp2f(z[0]);
            const float p1 = __builtin_amdgcn_exp2f(z[1]);
            const float p2 = __builtin_amdgcn_exp2f(z[2]);
            const float p3 = __builtin_amdgcn_exp2f(z[3]);
            l_lane += (p0 + p1) + (p2 + p3);
            uint2 pk;
            pk.x = pack2bf(p0, p1);
            pk.y = pack2bf(p2, p3);
            *(uint2*)&Ps[16 * w + qr][16 * si + quad * 4] = pk;   // ds_write_b64
        }

        // ---- PV: acc_o[c] += P @ V (wave-private Ps, no barrier) ----
        const short8 ap0 = *(const short8*)&Ps[16 * w + qr][quad * 8];
        const short8 ap1 = *(const short8*)&Ps[16 * w + qr][quad * 8 + 32];
        #pragma unroll
        for (int c = 0; c < 4; ++c) {
            const short8 bv0 = *(const short8*)&Vts[16 * c + qr][quad * 8];
            const short8 bv1 = *(const short8*)&Vts[16 * c + qr][quad * 8 + 32];
            acc_o[c] = __builtin_amdgcn_mfma_f32_16x16x32_bf16(ap0, bv0, acc_o[c], 0, 0, 0);
            acc_o[c] = __builtin_amdgcn_mfma_f32_16x16x32_bf16(ap1, bv1, acc_o[c], 0, 0, 0);
        }
    }

    // ---- final l reduction (across the 4 quads holding each qrow) ----
    l_lane += __shfl_xor(l_lane, 16);
    l_lane += __shfl_xor(l_lane, 32);
    float inv_l[4];
    #pragma unroll
    for (int r = 0; r < 4; ++r)
        inv_l[r] = 1.0f / __shfl(l_lane, quad * 4 + r);

    #pragma unroll
    for (int c = 0; c < 4; ++c)
        #pragma unroll
        for (int r = 0; r < 4; ++r)
            Hd[base + (size_t)(s0 + 16 * w + quad * 4 + r) * DQ + 16 * c + qr] =
                f2bf(acc_o[c][r] * inv_l[r]);
}

// ---------------------------------------------------------------------------
// kernel_launch
// Workspace (ushort units):
//   wt:    0        (3 x 262144)    qkv weights bf16, B^T [h*64+d][dd]
//   wo:    786432   (262144)        Wout bf16 [o][c]
//   q_ws:  1048576  (4194304)       q*QSCALE bf16 [b,h,s,d]
//   k_ws:  5242880  (4194304)       k bf16 [b,h,s,d]
//   vt_ws: 9437184  (4194304)       v bf16 [b,h,d,s]
//   h_ws:  13631488 (4194304)       heads bf16 (flat GEMM-A view)
// total ~34 MB
// ---------------------------------------------------------------------------
extern "C" void kernel_launch(void* const* d_in, const int* in_sizes, int n_in,
                              void* d_out, int out_size, void* d_ws, size_t ws_size,
                              hipStream_t stream) {
    const float* xq = (const float*)d_in[0];
    const float* xk = (const float*)d_in[1];
    const float* xv = (const float*)d_in[2];
    const float* Qw = (const float*)d_in[3];
    const float* Kw = (const float*)d_in[4];
    const float* Vw = (const float*)d_in[5];
    const float* Wo = (const float*)d_in[6];
    float* out = (float*)d_out;

    unsigned short* ws = (unsigned short*)d_ws;
    unsigned short* wt    = ws;
    unsigned short* wo    = ws + (size_t)786432;
    unsigned short* q_ws  = ws + (size_t)1048576;
    unsigned short* k_ws  = ws + (size_t)5242880;
    unsigned short* vt_ws = ws + (size_t)9437184;
    unsigned short* h_ws  = ws + (size_t)13631488;

    convert_w_kernel<<<dim3(256, 4), 256, 0, stream>>>(Qw, Kw, Vw, Wo, wt, wo);
    qkv_gemm_kernel<<<dim3(64, 4, 3), 256, 0, stream>>>(xq, xk, xv, wt, q_ws, k_ws, vt_ws);
    attn_kernel<<<dim3(SEQ / 64, NH, BATCH), 256, 0, stream>>>(q_ws, k_ws, vt_ws, h_ws);
    out_gemm_kernel<<<dim3(128, 4), 256, 0, stream>>>(h_ws, wo, out);
}

// Round 8
// 186.841 us; speedup vs baseline: 1.1517x; 1.0544x over previous
//
#include <hip/hip_runtime.h>
#include <math.h>

// Problem constants (B=4, S=2048, D_MODEL=512, H=8, DQ=64)
#define BATCH 4
#define SEQ   2048
#define DM    512
#define NH    8
#define DQ    64
#define BS    (BATCH*SEQ)     // 8192 rows
#define BPAD  72              // bf16 LDS row stride (144 B)
#define APAD  72              // padded tile stride in gemms

// q pre-scale: 1/sqrt(64) * log2(e), so softmax uses native 2^x (v_exp_f32)
#define QSCALE 0.18033688011112042f

typedef short  short8   __attribute__((ext_vector_type(8)));
typedef float  floatx4  __attribute__((ext_vector_type(4)));
typedef float  floatx16 __attribute__((ext_vector_type(16)));
typedef unsigned short ushort8 __attribute__((ext_vector_type(8)));

// cheap bf16: round-half-up (1 add + shift). Ties-only delta vs RNE.
__device__ __forceinline__ unsigned short f2bf(float f) {
    return (unsigned short)((__float_as_uint(f) + 0x8000u) >> 16);
}
// pack two floats -> two bf16 in one u32 (lo = a, hi = b): 2 adds + 1 v_perm
__device__ __forceinline__ unsigned pack2bf(float a, float b) {
    unsigned ua = __float_as_uint(a) + 0x8000u;
    unsigned ub = __float_as_uint(b) + 0x8000u;
    return __builtin_amdgcn_perm(ub, ua, 0x07060302u);  // {ub[3],ub[2],ua[3],ua[2]}
}

// ---------------------------------------------------------------------------
// convert_w: pack weights to bf16 B^T layout [n][k].
//   which 0..2: wt[which][h*64+d][dd] = W[h][dd][d]  (qkv projections)
//   which 3:    wo[o][c] = Wout[o][c]                 (already B^T)
// grid (256, 4).
// ---------------------------------------------------------------------------
__global__ __launch_bounds__(256) void convert_w_kernel(
    const float* __restrict__ Wq, const float* __restrict__ Wk,
    const float* __restrict__ Wv, const float* __restrict__ Wo,
    unsigned short* __restrict__ wt, unsigned short* __restrict__ wo)
{
    const int which = blockIdx.y;
    const int idx = blockIdx.x * 256 + threadIdx.x;   // 65536 per matrix
    if (which == 3) {
        float4 v = *(const float4*)(Wo + (size_t)idx * 4);
        uint2 o;
        o.x = pack2bf(v.x, v.y);
        o.y = pack2bf(v.z, v.w);
        *(uint2*)(wo + (size_t)idx * 4) = o;
    } else {
        const float* W = (which == 0) ? Wq : (which == 1) ? Wk : Wv;
        const int n   = idx >> 7;          // 0..511  (h*64+d)
        const int dd0 = (idx & 127) * 4;
        const int h = n >> 6, d = n & 63;
        uint2 o;
        o.x = pack2bf(W[((size_t)h * DM + dd0 + 0) * DQ + d],
                      W[((size_t)h * DM + dd0 + 1) * DQ + d]);
        o.y = pack2bf(W[((size_t)h * DM + dd0 + 2) * DQ + d],
                      W[((size_t)h * DM + dd0 + 3) * DQ + d]);
        *(uint2*)(wt + (size_t)which * (DM * DM) + (size_t)n * DM + dd0) = o;
    }
}

// ---------------------------------------------------------------------------
// qkv GEMM: 128x128 tile, BK=64, K=512 (8 k-steps). A (fp32 x, packed to
// bf16 at store) and B (bf16 weights) register-prefetched across the barrier.
// Outputs: which 0 -> q*QSCALE bf16 [b,h,s,d]; 1 -> k bf16 [b,h,s,d];
//          2 -> v bf16 [b,h,d,s].
// grid (64, 4, 3), block 256.
// ---------------------------------------------------------------------------
__global__ __launch_bounds__(256) void qkv_gemm_kernel(
    const float* __restrict__ Xq, const float* __restrict__ Xk,
    const float* __restrict__ Xv, const unsigned short* __restrict__ wt,
    unsigned short* __restrict__ Oq, unsigned short* __restrict__ Ok,
    unsigned short* __restrict__ Ovt)
{
    __shared__ unsigned short As[128][APAD];
    __shared__ unsigned short Bs[128][APAD];

    const int which = blockIdx.z;
    const float* X = (which == 0) ? Xq : (which == 1) ? Xk : Xv;
    const unsigned short* Bt = wt + (size_t)which * (DM * DM);

    const int m0 = blockIdx.x * 128;
    const int n0 = blockIdx.y * 128;
    const int t = threadIdx.x, w = t >> 6, lane = t & 63;
    const int quad = lane >> 4, qr = lane & 15;
    const int arow = t >> 4;           // A staging: 16 rows/pass
    const int acol = (t & 15) * 4;     // float4 col
    const int brow = t >> 3;           // B staging: 32 rows/pass
    const int bcol = (t & 7) * 8;      // ushort8 col
    const int mw = 64 * (w >> 1), nw = 64 * (w & 1);

    floatx4 acc[4][4] = {};
    float4  areg[8];
    ushort8 breg[4];

    #pragma unroll
    for (int i = 0; i < 8; ++i)
        areg[i] = *(const float4*)(X + (size_t)(m0 + i * 16 + arow) * DM + acol);
    #pragma unroll
    for (int i = 0; i < 4; ++i)
        breg[i] = *(const ushort8*)(Bt + (size_t)(n0 + i * 32 + brow) * DM + bcol);

    for (int k0 = 0; k0 < DM; k0 += 64) {
        __syncthreads();
        #pragma unroll
        for (int i = 0; i < 8; ++i) {
            uint2 o;
            o.x = pack2bf(areg[i].x, areg[i].y);
            o.y = pack2bf(areg[i].z, areg[i].w);
            *(uint2*)&As[i * 16 + arow][acol] = o;
        }
        #pragma unroll
        for (int i = 0; i < 4; ++i)
            *(ushort8*)&Bs[i * 32 + brow][bcol] = breg[i];
        __syncthreads();

        if (k0 + 64 < DM) {
            #pragma unroll
            for (int i = 0; i < 8; ++i)
                areg[i] = *(const float4*)(X + (size_t)(m0 + i * 16 + arow) * DM + k0 + 64 + acol);
            #pragma unroll
            for (int i = 0; i < 4; ++i)
                breg[i] = *(const ushort8*)(Bt + (size_t)(n0 + i * 32 + brow) * DM + k0 + 64 + bcol);
        }

        #pragma unroll
        for (int kh = 0; kh < 2; ++kh) {
            short8 af[4], bf[4];
            #pragma unroll
            for (int si = 0; si < 4; ++si)
                af[si] = *(const short8*)&As[mw + 16 * si + qr][kh * 32 + quad * 8];
            #pragma unroll
            for (int sj = 0; sj < 4; ++sj)
                bf[sj] = *(const short8*)&Bs[nw + 16 * sj + qr][kh * 32 + quad * 8];
            #pragma unroll
            for (int si = 0; si < 4; ++si)
                #pragma unroll
                for (int sj = 0; sj < 4; ++sj)
                    acc[si][sj] = __builtin_amdgcn_mfma_f32_16x16x32_bf16(
                        af[si], bf[sj], acc[si][sj], 0, 0, 0);
        }
    }

    const float osc = (which == 0) ? QSCALE : 1.0f;
    if (which < 2) {
        unsigned short* O = (which == 0) ? Oq : Ok;
        #pragma unroll
        for (int si = 0; si < 4; ++si) {
            #pragma unroll
            for (int sj = 0; sj < 4; ++sj) {
                const int col = n0 + nw + 16 * sj + qr;
                const int h = col >> 6, d = col & 63;
                #pragma unroll
                for (int r = 0; r < 4; ++r) {
                    const int row = m0 + mw + 16 * si + quad * 4 + r;
                    const int b = row >> 11, s = row & (SEQ - 1);
                    O[((size_t)(b * NH + h) * SEQ + s) * DQ + d] = f2bf(acc[si][sj][r] * osc);
                }
            }
        }
    } else {
        #pragma unroll
        for (int si = 0; si < 4; ++si) {
            #pragma unroll
            for (int sj = 0; sj < 4; ++sj) {
                const int col = n0 + nw + 16 * sj + qr;
                const int h = col >> 6, d = col & 63;
                #pragma unroll
                for (int r = 0; r < 4; ++r) {
                    const int row = m0 + mw + 16 * si + quad * 4 + r;
                    const int b = row >> 11, s = row & (SEQ - 1);
                    Ovt[((size_t)(b * NH + h) * DQ + d) * SEQ + s] = f2bf(acc[si][sj][r]);
                }
            }
        }
    }
}

// ---------------------------------------------------------------------------
// out GEMM: 64x128 tile (512 blocks = 2/CU), BK=64, register-prefetched.
// A = heads bf16 [8192x512] (flat view == reference reshape), Bt = Wout bf16
// [o][c]. Output fp32 d_out. grid (128, 4), block 256; wave tile 32x64.
// ---------------------------------------------------------------------------
__global__ __launch_bounds__(256) void out_gemm_kernel(
    const unsigned short* __restrict__ A, const unsigned short* __restrict__ Bt,
    float* __restrict__ C)
{
    __shared__ unsigned short As[64][APAD];
    __shared__ unsigned short Bs[128][APAD];

    const int m0 = blockIdx.x * 64;
    const int n0 = blockIdx.y * 128;
    const int t = threadIdx.x, w = t >> 6, lane = t & 63;
    const int quad = lane >> 4, qr = lane & 15;
    const int brow = t >> 3;           // 32 rows/pass
    const int bcol = (t & 7) * 8;
    const int mw = 32 * (w >> 1), nw = 64 * (w & 1);

    floatx4 acc[2][4] = {};
    ushort8 areg[2], breg[4];

    #pragma unroll
    for (int i = 0; i < 2; ++i)
        areg[i] = *(const ushort8*)(A + (size_t)(m0 + i * 32 + brow) * DM + bcol);
    #pragma unroll
    for (int i = 0; i < 4; ++i)
        breg[i] = *(const ushort8*)(Bt + (size_t)(n0 + i * 32 + brow) * DM + bcol);

    for (int k0 = 0; k0 < DM; k0 += 64) {
        __syncthreads();
        #pragma unroll
        for (int i = 0; i < 2; ++i)
            *(ushort8*)&As[i * 32 + brow][bcol] = areg[i];
        #pragma unroll
        for (int i = 0; i < 4; ++i)
            *(ushort8*)&Bs[i * 32 + brow][bcol] = breg[i];
        __syncthreads();

        if (k0 + 64 < DM) {
            #pragma unroll
            for (int i = 0; i < 2; ++i)
                areg[i] = *(const ushort8*)(A + (size_t)(m0 + i * 32 + brow) * DM + k0 + 64 + bcol);
            #pragma unroll
            for (int i = 0; i < 4; ++i)
                breg[i] = *(const ushort8*)(Bt + (size_t)(n0 + i * 32 + brow) * DM + k0 + 64 + bcol);
        }

        #pragma unroll
        for (int kh = 0; kh < 2; ++kh) {
            short8 af[2], bf[4];
            #pragma unroll
            for (int si = 0; si < 2; ++si)
                af[si] = *(const short8*)&As[mw + 16 * si + qr][kh * 32 + quad * 8];
            #pragma unroll
            for (int sj = 0; sj < 4; ++sj)
                bf[sj] = *(const short8*)&Bs[nw + 16 * sj + qr][kh * 32 + quad * 8];
            #pragma unroll
            for (int si = 0; si < 2; ++si)
                #pragma unroll
                for (int sj = 0; sj < 4; ++sj)
                    acc[si][sj] = __builtin_amdgcn_mfma_f32_16x16x32_bf16(
                        af[si], bf[sj], acc[si][sj], 0, 0, 0);
        }
    }

    #pragma unroll
    for (int si = 0; si < 2; ++si) {
        #pragma unroll
        for (int sj = 0; sj < 4; ++sj) {
            const int col = n0 + nw + 16 * sj + qr;
            #pragma unroll
            for (int r = 0; r < 4; ++r) {
                const int row = m0 + mw + 16 * si + quad * 4 + r;
                C[(size_t)row * DM + col] = acc[si][sj][r];
            }
        }
    }
}

// ---------------------------------------------------------------------------
// flash attention v6: 32x32x16 MFMA (2x matrix data per ds_read_b128 — the
// kernel is LDS-throughput bound: R7 model 1152 LDS-cy/block-iter at 88%
// pipe utilization; this cuts fragment reads 18 -> 10 b128 per wave-iter).
// Block = 64 q-rows; wave (qh = w>>1, kh = w&1) computes S^T[32kv][32q] for
// its q-half x kv-half, P round-trips through a wave-private Ps quadrant
// (no extra barriers), PV gives per-wave partial O[32q][64dv]; kh pairs
// combine O and l once at the end through LDS aliased over dead K/V tiles.
// Fixed-reference base-2 softmax, raw v_exp_f32, K/V register prefetch.
// 36 KB LDS -> 4 blocks/CU. grid = (32, 8, 4), block 256.
// MFMA 32x32x16 layouts: A[m=lane&31][k=(lane>>5)*8+j],
// B[k=(lane>>5)*8+j][n=lane&31], C/D col=lane&31,
// row=(reg&3)+8*(reg>>2)+4*(lane>>5)  (C/D HW-verified m74/m101).
// ---------------------------------------------------------------------------
__global__ __launch_bounds__(256, 4) void attn_kernel(
    const unsigned short* __restrict__ Qp, const unsigned short* __restrict__ Kp,
    const unsigned short* __restrict__ Vtp, unsigned short* __restrict__ Hd)
{
    __shared__ unsigned short smem[4 * 64 * BPAD];   // 36 KB
    unsigned short (*Qs)[BPAD]  = (unsigned short (*)[BPAD])(smem);
    unsigned short (*Ks)[BPAD]  = (unsigned short (*)[BPAD])(smem + 64 * BPAD);
    unsigned short (*Vts)[BPAD] = (unsigned short (*)[BPAD])(smem + 2 * 64 * BPAD);
    unsigned short (*Ps)[BPAD]  = (unsigned short (*)[BPAD])(smem + 3 * 64 * BPAD);

    const int s0 = blockIdx.x * 64;
    const int h  = blockIdx.y;
    const int b  = blockIdx.z;
    const size_t bh    = (size_t)(b * NH + h);
    const size_t base  = bh * SEQ * DQ;       // [b,h,s,d]
    const size_t vbase = bh * DQ * SEQ;       // [b,h,d,s]

    const int t    = threadIdx.x;
    const int w    = t >> 6;
    const int lane = t & 63;
    const int qh   = w >> 1;      // q-half (rows 32qh..32qh+31)
    const int kh   = w & 1;       // kv-half within each 64-kv tile
    const int ln31 = lane & 31;
    const int lh   = lane >> 5;   // lane half

    // ---- stage Q tile ----
    {
        const unsigned short* g = Qp + base + (size_t)s0 * DQ;
        #pragma unroll
        for (int i = 0; i < 2; ++i) {
            const int c = t + 256 * i;
            const int row = c >> 3, col8 = (c & 7) * 8;
            *(ushort8*)&Qs[row][col8] = *(const ushort8*)(g + row * DQ + col8);
        }
    }
    __syncthreads();
    // hoist Q B-fragments: B[k=d][n=q], q = 32qh + ln31
    short8 bq[4];
    #pragma unroll
    for (int s = 0; s < 4; ++s)
        bq[s] = *(const short8*)&Qs[32 * qh + ln31][16 * s + lh * 8];

    floatx16 accO[2] = {};   // partial O[32q][64dv]: a=dv-block; lane col=dv
    float l_lane = 0.f;

    // ---- prefetch first K/V tile into registers ----
    ushort8 kreg[2], vreg[2];
    {
        const unsigned short* gk = Kp + base;
        const unsigned short* gv = Vtp + vbase;
        #pragma unroll
        for (int i = 0; i < 2; ++i) {
            const int c = t + 256 * i;
            const int row = c >> 3, col8 = (c & 7) * 8;
            kreg[i] = *(const ushort8*)(gk + row * DQ + col8);
            vreg[i] = *(const ushort8*)(gv + (size_t)row * SEQ + col8);
        }
    }

    for (int kt = 0; kt < SEQ; kt += 64) {
        __syncthreads();   // prev iteration's reads of Ks/Vts complete
        #pragma unroll
        for (int i = 0; i < 2; ++i) {
            const int c = t + 256 * i;
            const int row = c >> 3, col8 = (c & 7) * 8;
            *(ushort8*)&Ks[row][col8]  = kreg[i];
            *(ushort8*)&Vts[row][col8] = vreg[i];
        }
        __syncthreads();

        if (kt + 64 < SEQ) {
            const unsigned short* gk = Kp + base + (size_t)(kt + 64) * DQ;
            const unsigned short* gv = Vtp + vbase + (kt + 64);
            #pragma unroll
            for (int i = 0; i < 2; ++i) {
                const int c = t + 256 * i;
                const int row = c >> 3, col8 = (c & 7) * 8;
                kreg[i] = *(const ushort8*)(gk + row * DQ + col8);
                vreg[i] = *(const ushort8*)(gv + (size_t)row * SEQ + col8);
            }
        }

        // ---- S^T[32kv][32q] = K-half @ Q-half^T (4-chain over d=64) ----
        floatx16 z = {};
        #pragma unroll
        for (int s = 0; s < 4; ++s) {
            const short8 ak = *(const short8*)&Ks[32 * kh + ln31][16 * s + lh * 8];
            z = __builtin_amdgcn_mfma_f32_32x32x16_bf16(ak, bq[s], z, 0, 0, 0);
        }

        // ---- exp2, l accumulate, pack P (reg 4g+r -> kv = 8g+4lh+r) ----
        #pragma unroll
        for (int g = 0; g < 4; ++g) {
            const float p0 = __builtin_amdgcn_exp2f(z[4 * g + 0]);
            const float p1 = __builtin_amdgcn_exp2f(z[4 * g + 1]);
            const float p2 = __builtin_amdgcn_exp2f(z[4 * g + 2]);
            const float p3 = __builtin_amdgcn_exp2f(z[4 * g + 3]);
            l_lane += (p0 + p1) + (p2 + p3);
            uint2 pk;
            pk.x = pack2bf(p0, p1);
            pk.y = pack2bf(p2, p3);
            *(uint2*)&Ps[32 * qh + ln31][32 * kh + 8 * g + 4 * lh] = pk;
        }

        // ---- PV: accO[a] += P[32q][32kv] @ V[32kv][32dv] ----
        short8 ap[2];
        ap[0] = *(const short8*)&Ps[32 * qh + ln31][32 * kh + lh * 8];
        ap[1] = *(const short8*)&Ps[32 * qh + ln31][32 * kh + 16 + lh * 8];
        #pragma unroll
        for (int a = 0; a < 2; ++a) {
            #pragma unroll
            for (int s = 0; s < 2; ++s) {
                const short8 bv = *(const short8*)&Vts[32 * a + ln31][32 * kh + 16 * s + lh * 8];
                accO[a] = __builtin_amdgcn_mfma_f32_32x32x16_bf16(ap[s], bv, accO[a], 0, 0, 0);
            }
        }
    }

    // ---- cross-kh combine: O and l, via LDS aliased over dead K/V tiles ----
    float l2 = l_lane + __shfl_xor(l_lane, 32);   // full kv-half sum for q=32qh+ln31
    float* Obuf = (float*)(smem + 64 * BPAD);     // 64x66 f32 = 16.9 KB over Ks+Vts (18.4 KB)
    float* lbuf = (float*)(smem + 3 * 64 * BPAD); // over Ps: [0..63] kh0-l, [64..127] inv_l
    __syncthreads();                              // all LDS reads of the loop done

    if (kh == 0) {
        if (lane < 32) lbuf[qh * 32 + lane] = l2;
        #pragma unroll
        for (int a = 0; a < 2; ++a)
            #pragma unroll
            for (int r = 0; r < 16; ++r) {
                const int qrow = (r & 3) + 8 * (r >> 2) + 4 * lh;
                Obuf[(32 * qh + qrow) * 66 + 32 * a + ln31] = accO[a][r];
            }
    }
    __syncthreads();

    if (kh == 1) {
        const float ltot = l2 + lbuf[qh * 32 + ln31];
        if (lane < 32) lbuf[64 + qh * 32 + lane] = 1.0f / ltot;  // same-wave RAW
        #pragma unroll
        for (int a = 0; a < 2; ++a)
            #pragma unroll
            for (int r = 0; r < 16; ++r) {
                const int qrow = (r & 3) + 8 * (r >> 2) + 4 * lh;
                const float o = accO[a][r] + Obuf[(32 * qh + qrow) * 66 + 32 * a + ln31];
                const float iv = lbuf[64 + qh * 32 + qrow];
                Hd[base + (size_t)(s0 + 32 * qh + qrow) * DQ + 32 * a + ln31] = f2bf(o * iv);
            }
    }
}

// ---------------------------------------------------------------------------
// kernel_launch
// Workspace (ushort units):
//   wt:    0        (3 x 262144)    qkv weights bf16, B^T [h*64+d][dd]
//   wo:    786432   (262144)        Wout bf16 [o][c]
//   q_ws:  1048576  (4194304)       q*QSCALE bf16 [b,h,s,d]
//   k_ws:  5242880  (4194304)       k bf16 [b,h,s,d]
//   vt_ws: 9437184  (4194304)       v bf16 [b,h,d,s]
//   h_ws:  13631488 (4194304)       heads bf16 (flat GEMM-A view)
// total ~34 MB
// ---------------------------------------------------------------------------
extern "C" void kernel_launch(void* const* d_in, const int* in_sizes, int n_in,
                              void* d_out, int out_size, void* d_ws, size_t ws_size,
                              hipStream_t stream) {
    const float* xq = (const float*)d_in[0];
    const float* xk = (const float*)d_in[1];
    const float* xv = (const float*)d_in[2];
    const float* Qw = (const float*)d_in[3];
    const float* Kw = (const float*)d_in[4];
    const float* Vw = (const float*)d_in[5];
    const float* Wo = (const float*)d_in[6];
    float* out = (float*)d_out;

    unsigned short* ws = (unsigned short*)d_ws;
    unsigned short* wt    = ws;
    unsigned short* wo    = ws + (size_t)786432;
    unsigned short* q_ws  = ws + (size_t)1048576;
    unsigned short* k_ws  = ws + (size_t)5242880;
    unsigned short* vt_ws = ws + (size_t)9437184;
    unsigned short* h_ws  = ws + (size_t)13631488;

    convert_w_kernel<<<dim3(256, 4), 256, 0, stream>>>(Qw, Kw, Vw, Wo, wt, wo);
    qkv_gemm_kernel<<<dim3(64, 4, 3), 256, 0, stream>>>(xq, xk, xv, wt, q_ws, k_ws, vt_ws);
    attn_kernel<<<dim3(SEQ / 64, NH, BATCH), 256, 0, stream>>>(q_ws, k_ws, vt_ws, h_ws);
    out_gemm_kernel<<<dim3(128, 4), 256, 0, stream>>>(h_ws, wo, out);
}